// Round 1
// baseline (100.283 us; speedup 1.0000x reference)
//
#include <hip/hip_runtime.h>

// Problem constants: N=16, C=256, K=6, M=22, Ho=17
#define NB   16
#define CC   256
#define KK   6
#define MM   22
#define HO   17           // M - K + 1
#define NPQ  (HO*HO)      // 289 outputs per batch image
#define TOT  (NB*NPQ)     // 4624 total outputs
#define CHN  8            // channels per block
#define CGRP (CC/CHN)     // 32 channel-groups
#define XPC  (MM*MM)      // 484 x-elements per channel
#define ZPC  (KK*KK)      // 36 z-elements per channel
#define XSTR 24           // padded LDS row stride (16B-aligned rows)
#define XCH  548          // padded LDS channel stride: %32==4 (bank spread), %4==0
#define RCH  292          // reduction buffer channel stride: %32==4
#define PSTR 292          // partial-row stride in workspace (289 padded, 16B-mult)

// Kernel A: per-(batch, channel-group) correlation, register-tiled.
// Writes an 8-channel partial sum to a PRIVATE workspace row — no atomics,
// no zero-init required (row is fully overwritten; poison-safe), no memset
// dispatch on the critical path.
__global__ __launch_bounds__(256) void corr_kernel(
    const float* __restrict__ z, const float* __restrict__ x,
    const float* __restrict__ w, float* __restrict__ P)
{
    __shared__ float szw[CHN * ZPC];    // w_c * sqrt(z)
    __shared__ float sx [CHN * XCH];    // sqrt(x), padded
    __shared__ float red[CHN * RCH];    // per-channel row results

    const int b  = blockIdx.x;
    const int n  = b >> 5;              // / CGRP
    const int cg = b & 31;              // % CGRP
    const int c0 = cg * CHN;
    const int t  = threadIdx.x;

    const float* zb = z + (size_t)(n * CC + c0) * ZPC;
    const float* xb = x + (size_t)(n * CC + c0) * XPC;

    // Stage w*sqrt(z): 288 contiguous floats
    for (int e = t; e < CHN * ZPC; e += 256) {
        int c = e / ZPC;
        szw[e] = sqrtf(zb[e]) * w[c0 + c];
    }
    // Stage sqrt(x) into padded rows (float2: odd global rows are 8B-aligned)
    {
        const float2* xb2 = reinterpret_cast<const float2*>(xb);
        for (int e = t; e < CHN * XPC / 2; e += 256) {   // 1936 float2
            int ch  = e / 242;
            int r   = e - ch * 242;
            int row = r / 11;
            int col = (r - row * 11) * 2;
            float2 v = xb2[e];
            float* dst = &sx[ch * XCH + row * XSTR + col];
            dst[0] = sqrtf(v.x);
            dst[1] = sqrtf(v.y);
        }
    }
    __syncthreads();

    if (t < HO * CHN) {                 // 136 active threads
        const int p  = t >> 3;          // 0..16
        const int ch = t & 7;

        // z fragment -> registers (9 b128)
        float zr[36];
        const float4* z4 = reinterpret_cast<const float4*>(&szw[ch * ZPC]);
        #pragma unroll
        for (int k = 0; k < 9; ++k) {
            float4 v = z4[k];
            zr[4*k] = v.x; zr[4*k+1] = v.y; zr[4*k+2] = v.z; zr[4*k+3] = v.w;
        }

        float a[HO];
        #pragma unroll
        for (int q = 0; q < HO; ++q) a[q] = 0.f;

        #pragma unroll
        for (int i = 0; i < KK; ++i) {
            float xr[24];
            const float4* row4 =
                reinterpret_cast<const float4*>(&sx[ch * XCH + (p + i) * XSTR]);
            #pragma unroll
            for (int k = 0; k < 6; ++k) {
                float4 v = row4[k];
                xr[4*k] = v.x; xr[4*k+1] = v.y; xr[4*k+2] = v.z; xr[4*k+3] = v.w;
            }
            #pragma unroll
            for (int j = 0; j < KK; ++j) {
                float zv = zr[i * KK + j];
                #pragma unroll
                for (int q = 0; q < HO; ++q)
                    a[q] += zv * xr[q + j];
            }
        }
        float* rr = &red[ch * RCH + p * HO];
        #pragma unroll
        for (int q = 0; q < HO; ++q) rr[q] = a[q];
    }
    __syncthreads();

    // Sum the 8 channels, pre-scale by 1/36, write private partial row.
    // 289 coalesced stores per block; zero contention.
    float* pb = P + (size_t)(n * CGRP + cg) * PSTR;
    for (int idx = t; idx < NPQ; idx += 256) {
        float s = 0.f;
        #pragma unroll
        for (int ch = 0; ch < CHN; ++ch) s += red[ch * RCH + idx];
        pb[idx] = s * (1.0f / 36.0f);
    }
}

// Kernel B: reduce the 32 channel-group partials per output (592 KB coalesced
// L2 reads), double-precision stats, normalize from registers, write out.
__global__ __launch_bounds__(512) void bn_kernel(
    const float* __restrict__ P, const float* __restrict__ bnw,
    const float* __restrict__ bnb, float* __restrict__ out)
{
    __shared__ double sred[16];
    __shared__ float  fstat[2];
    const int t = threadIdx.x;

    // Each thread owns outputs t, t+512, ... (<=10). For each output,
    // sum 32 partials at stride PSTR — per g-iteration the wave reads 64
    // consecutive dwords (fully coalesced).
    float v[10];
    double ls = 0.0, ls2 = 0.0;
    #pragma unroll
    for (int k = 0; k < 10; ++k) {
        const int idx = t + (k << 9);
        float s = 0.f;
        if (idx < TOT) {
            const int n = idx / NPQ;
            const int q = idx - n * NPQ;
            const float* pb = P + (size_t)(n * CGRP) * PSTR + q;
            #pragma unroll
            for (int g = 0; g < CGRP; ++g) s += pb[g * PSTR];
        }
        v[k] = s;
        double ds = (double)s;
        ls  += ds;
        ls2 += ds * ds;
    }

    #pragma unroll
    for (int off = 32; off > 0; off >>= 1) {
        ls  += __shfl_down(ls,  off, 64);
        ls2 += __shfl_down(ls2, off, 64);
    }
    if ((t & 63) == 0) { sred[(t >> 6) * 2] = ls; sred[(t >> 6) * 2 + 1] = ls2; }
    __syncthreads();
    if (t == 0) {
        double S = 0.0, S2 = 0.0;
        #pragma unroll
        for (int wv = 0; wv < 8; ++wv) { S += sred[2 * wv]; S2 += sred[2 * wv + 1]; }
        double mu  = S / (double)TOT;
        double var = S2 / (double)TOT - mu * mu;
        fstat[0] = (float)mu;
        fstat[1] = (float)(1.0 / sqrt(var + 1e-5)) * bnw[0];
    }
    __syncthreads();

    const float mu    = fstat[0];
    const float scale = fstat[1];
    const float bias  = bnb[0];
    #pragma unroll
    for (int k = 0; k < 10; ++k) {
        const int idx = t + (k << 9);
        if (idx < TOT) out[idx] = (v[k] - mu) * scale + bias;
    }
}

extern "C" void kernel_launch(void* const* d_in, const int* in_sizes, int n_in,
                              void* d_out, int out_size, void* d_ws, size_t ws_size,
                              hipStream_t stream) {
    const float* z   = (const float*)d_in[0];   // [16,256,6,6]
    const float* x   = (const float*)d_in[1];   // [16,256,22,22]
    const float* w   = (const float*)d_in[2];   // [1,256,1,1,1] -> 256
    const float* bnw = (const float*)d_in[3];   // [1]
    const float* bnb = (const float*)d_in[4];   // [1]
    float* out = (float*)d_out;                 // [16,1,17,17] -> 4624
    float* P   = (float*)d_ws;                  // [16*32][292] partial rows

    // No memset: partial rows are fully overwritten before being read.
    corr_kernel<<<NB * CGRP, 256, 0, stream>>>(z, x, w, P);
    bn_kernel<<<1, 512, 0, stream>>>(P, bnw, bnb, out);
}

// Round 2
// 78.595 us; speedup vs baseline: 1.2760x; 1.2760x over previous
//
#include <hip/hip_runtime.h>

// Problem constants: N=16, C=256, K=6, M=22, Ho=17
#define NB   16
#define CC   256
#define KK   6
#define MM   22
#define HO   17           // M - K + 1
#define NPQ  (HO*HO)      // 289 outputs per batch image
#define TOT  (NB*NPQ)     // 4624 total outputs
#define CHN  8            // channels per block
#define CGRP (CC/CHN)     // 32 channel-groups
#define XPC  (MM*MM)      // 484 x-elements per channel
#define ZPC  (KK*KK)      // 36 z-elements per channel
#define XSTR 24           // padded LDS row stride (16B-aligned rows)
#define XCH  548          // padded LDS channel stride: %32==4 (bank spread), %4==0
#define RCH  292          // reduction buffer channel stride: %32==4
#define PSTR 292          // partial-row stride in workspace (289 padded, 16B-mult)

// Workspace layout (floats unless noted):
//   P     @ 0                : [NB*CGRP][PSTR] = 512*292 partial rows
//   mean  @ MEAN_OFF         : [TOT] packed per-output channel sums (/36)
//   stats @ STATS_OFF (dbl)  : [NB][2] per-image (S, S2) double partials
#define MEAN_OFF  (NB * CGRP * PSTR)              // 149504 floats (byte 598016)
#define STATS_OFF ((MEAN_OFF + TOT) / 2)          // double index: byte 616512, 8-aligned

// Kernel A: per-(batch, channel-group) correlation, register-tiled.
// UNCHANGED verified staging/compute. Writes a private partial row
// (fully overwritten -> poison-safe, no memset, no atomics).
__global__ __launch_bounds__(256) void corr_kernel(
    const float* __restrict__ z, const float* __restrict__ x,
    const float* __restrict__ w, float* __restrict__ P)
{
    __shared__ float szw[CHN * ZPC];    // w_c * sqrt(z)
    __shared__ float sx [CHN * XCH];    // sqrt(x), padded
    __shared__ float red[CHN * RCH];    // per-channel row results

    const int b  = blockIdx.x;
    const int n  = b >> 5;              // / CGRP
    const int cg = b & 31;              // % CGRP
    const int c0 = cg * CHN;
    const int t  = threadIdx.x;

    const float* zb = z + (size_t)(n * CC + c0) * ZPC;
    const float* xb = x + (size_t)(n * CC + c0) * XPC;

    // Stage w*sqrt(z): 288 contiguous floats
    for (int e = t; e < CHN * ZPC; e += 256) {
        int c = e / ZPC;
        szw[e] = sqrtf(zb[e]) * w[c0 + c];
    }
    // Stage sqrt(x) into padded rows (float2: odd global rows are 8B-aligned)
    {
        const float2* xb2 = reinterpret_cast<const float2*>(xb);
        for (int e = t; e < CHN * XPC / 2; e += 256) {   // 1936 float2
            int ch  = e / 242;
            int r   = e - ch * 242;
            int row = r / 11;
            int col = (r - row * 11) * 2;
            float2 v = xb2[e];
            float* dst = &sx[ch * XCH + row * XSTR + col];
            dst[0] = sqrtf(v.x);
            dst[1] = sqrtf(v.y);
        }
    }
    __syncthreads();

    if (t < HO * CHN) {                 // 136 active threads
        const int p  = t >> 3;          // 0..16
        const int ch = t & 7;

        // z fragment -> registers (9 b128)
        float zr[36];
        const float4* z4 = reinterpret_cast<const float4*>(&szw[ch * ZPC]);
        #pragma unroll
        for (int k = 0; k < 9; ++k) {
            float4 v = z4[k];
            zr[4*k] = v.x; zr[4*k+1] = v.y; zr[4*k+2] = v.z; zr[4*k+3] = v.w;
        }

        float a[HO];
        #pragma unroll
        for (int q = 0; q < HO; ++q) a[q] = 0.f;

        #pragma unroll
        for (int i = 0; i < KK; ++i) {
            float xr[24];
            const float4* row4 =
                reinterpret_cast<const float4*>(&sx[ch * XCH + (p + i) * XSTR]);
            #pragma unroll
            for (int k = 0; k < 6; ++k) {
                float4 v = row4[k];
                xr[4*k] = v.x; xr[4*k+1] = v.y; xr[4*k+2] = v.z; xr[4*k+3] = v.w;
            }
            #pragma unroll
            for (int j = 0; j < KK; ++j) {
                float zv = zr[i * KK + j];
                #pragma unroll
                for (int q = 0; q < HO; ++q)
                    a[q] += zv * xr[q + j];
            }
        }
        float* rr = &red[ch * RCH + p * HO];
        #pragma unroll
        for (int q = 0; q < HO; ++q) rr[q] = a[q];
    }
    __syncthreads();

    // Sum the 8 channels, pre-scale by 1/36, write private partial row.
    float* pb = P + (size_t)(n * CGRP + cg) * PSTR;
    for (int idx = t; idx < NPQ; idx += 256) {
        float s = 0.f;
        #pragma unroll
        for (int ch = 0; ch < CHN; ++ch) s += red[ch * RCH + idx];
        pb[idx] = s * (1.0f / 36.0f);
    }
}

// Kernel B: per-image reduction of the 32 channel-group partials.
// 16 blocks x 256 threads; each block reads its own 37 KB (per-instruction
// coalesced, 16 CUs of gather bandwidth vs round-1's single CU), writes the
// packed mean row and a per-image (S, S2) double partial.
__global__ __launch_bounds__(256) void reduce_kernel(
    const float* __restrict__ P, float* __restrict__ mean,
    double* __restrict__ stats)
{
    __shared__ double sred[8];
    const int n = blockIdx.x;
    const int t = threadIdx.x;
    const float* pb = P + (size_t)n * CGRP * PSTR;

    double ls = 0.0, ls2 = 0.0;
    #pragma unroll
    for (int k = 0; k < 2; ++k) {
        const int q = t + (k << 8);
        if (q < NPQ) {
            float s = 0.f;
            #pragma unroll
            for (int g = 0; g < CGRP; ++g) s += pb[g * PSTR + q];
            mean[n * NPQ + q] = s;
            double ds = (double)s;
            ls  += ds;
            ls2 += ds * ds;
        }
    }
    #pragma unroll
    for (int off = 32; off > 0; off >>= 1) {
        ls  += __shfl_down(ls,  off, 64);
        ls2 += __shfl_down(ls2, off, 64);
    }
    if ((t & 63) == 0) { sred[(t >> 6) * 2] = ls; sred[(t >> 6) * 2 + 1] = ls2; }
    __syncthreads();
    if (t == 0) {
        double S = 0.0, S2 = 0.0;
        #pragma unroll
        for (int wv = 0; wv < 4; ++wv) { S += sred[2 * wv]; S2 += sred[2 * wv + 1]; }
        stats[n * 2]     = S;
        stats[n * 2 + 1] = S2;
    }
}

// Kernel C: combine 16 stat partials (broadcast loads), normalize the packed
// mean array (18.5 KB contiguous float4 -- the round-0 known-fast pattern).
__global__ __launch_bounds__(512) void bn_kernel(
    const float* __restrict__ mean, const double* __restrict__ stats,
    const float* __restrict__ bnw, const float* __restrict__ bnb,
    float* __restrict__ out)
{
    const int t = threadIdx.x;

    double S = 0.0, S2 = 0.0;
    #pragma unroll
    for (int n = 0; n < NB; ++n) { S += stats[2 * n]; S2 += stats[2 * n + 1]; }
    const double mu  = S / (double)TOT;
    const double var = S2 / (double)TOT - mu * mu;
    const float fmu   = (float)mu;
    const float scale = (float)(1.0 / sqrt(var + 1e-5)) * bnw[0];
    const float bias  = bnb[0];

    const float4* m4 = reinterpret_cast<const float4*>(mean);
    float4* o4 = reinterpret_cast<float4*>(out);
    for (int i = t; i < TOT / 4; i += 512) {   // 1156 float4, exact
        float4 v = m4[i];
        v.x = (v.x - fmu) * scale + bias;
        v.y = (v.y - fmu) * scale + bias;
        v.z = (v.z - fmu) * scale + bias;
        v.w = (v.w - fmu) * scale + bias;
        o4[i] = v;
    }
}

extern "C" void kernel_launch(void* const* d_in, const int* in_sizes, int n_in,
                              void* d_out, int out_size, void* d_ws, size_t ws_size,
                              hipStream_t stream) {
    const float* z   = (const float*)d_in[0];   // [16,256,6,6]
    const float* x   = (const float*)d_in[1];   // [16,256,22,22]
    const float* w   = (const float*)d_in[2];   // [1,256,1,1,1] -> 256
    const float* bnw = (const float*)d_in[3];   // [1]
    const float* bnb = (const float*)d_in[4];   // [1]
    float* out = (float*)d_out;                 // [16,1,17,17] -> 4624

    float*  P     = (float*)d_ws;
    float*  mean  = (float*)d_ws + MEAN_OFF;
    double* stats = (double*)d_ws + STATS_OFF;

    // No memset: every workspace word consumed is written first this launch.
    corr_kernel  <<<NB * CGRP, 256, 0, stream>>>(z, x, w, P);
    reduce_kernel<<<NB,        256, 0, stream>>>(P, mean, stats);
    bn_kernel    <<<1,         512, 0, stream>>>(mean, stats, bnw, bnb, out);
}